// Round 5
// baseline (105.078 us; speedup 1.0000x reference)
//
#include <hip/hip_runtime.h>

#define DIM 64

typedef int          vint4   __attribute__((ext_vector_type(4)));
typedef unsigned int vuint2  __attribute__((ext_vector_type(2)));
typedef unsigned int vuint4  __attribute__((ext_vector_type(4)));
typedef float        vfloat4 __attribute__((ext_vector_type(4)));

// ---------------- Kernel A: global max|X| (abs-bits + uint atomicMax) ----------------
// For non-negative IEEE floats, uint compare == float compare. Deterministic.
__global__ void __launch_bounds__(256) absmax_kernel(
        const float* __restrict__ X, unsigned int* __restrict__ maxbits, int n4) {
    const vuint4* Xu = reinterpret_cast<const vuint4*>(X);
    unsigned int m = 0;
    int i = blockIdx.x * blockDim.x + threadIdx.x;
    const int str = gridDim.x * blockDim.x;
    for (; i < n4; i += str) {
        const vuint4 v = Xu[i];
        m = max(m, v.x & 0x7fffffffu);
        m = max(m, v.y & 0x7fffffffu);
        m = max(m, v.z & 0x7fffffffu);
        m = max(m, v.w & 0x7fffffffu);
    }
    for (int off = 32; off > 0; off >>= 1)
        m = max(m, (unsigned int)__shfl_xor((int)m, off, 64));
    if ((threadIdx.x & 63) == 0) atomicMax(maxbits, m);
}

// ---------------- Kernel B: quantize X -> int8, scale = max/127 ----------------
__device__ __forceinline__ unsigned int pack4_i8(const vfloat4& f, float inv) {
    const int q0 = (int)rintf(f.x * inv);
    const int q1 = (int)rintf(f.y * inv);
    const int q2 = (int)rintf(f.z * inv);
    const int q3 = (int)rintf(f.w * inv);
    return (unsigned int)(q0 & 0xff) | ((unsigned int)(q1 & 0xff) << 8) |
           ((unsigned int)(q2 & 0xff) << 16) | ((unsigned int)(q3 & 0xff) << 24);
}

__global__ void __launch_bounds__(256) quantize_kernel(
        const float* __restrict__ X, const unsigned int* __restrict__ maxbits,
        unsigned int* __restrict__ Xq, int n16) {
    int i = blockIdx.x * blockDim.x + threadIdx.x;
    if (i >= n16) return;
    const float inv = 127.0f / __uint_as_float(*maxbits);
    const vfloat4* Xf = reinterpret_cast<const vfloat4*>(X);
    const vfloat4 a = Xf[(size_t)i * 4 + 0];
    const vfloat4 b = Xf[(size_t)i * 4 + 1];
    const vfloat4 c = Xf[(size_t)i * 4 + 2];
    const vfloat4 d = Xf[(size_t)i * 4 + 3];
    vuint4 o;
    o.x = pack4_i8(a, inv);
    o.y = pack4_i8(b, inv);
    o.z = pack4_i8(c, inv);
    o.w = pack4_i8(d, inv);
    reinterpret_cast<vuint4*>(Xq)[i] = o;
}

// ---------------- Score kernel ----------------
// 8 features per lane as int8: exact int16 product s*t, fp32 weight by R.
__device__ __forceinline__ float dot8_i8(const vuint2& s, const vuint2& t,
                                         const vfloat4& ra, const vfloat4& rb) {
    float acc = 0.f;
    int p;
    p = ((int)(s.x << 24) >> 24) * ((int)(t.x << 24) >> 24); acc = fmaf((float)p, ra.x, acc);
    p = ((int)(s.x << 16) >> 24) * ((int)(t.x << 16) >> 24); acc = fmaf((float)p, ra.y, acc);
    p = ((int)(s.x <<  8) >> 24) * ((int)(t.x <<  8) >> 24); acc = fmaf((float)p, ra.z, acc);
    p = ((int)(s.x      ) >> 24) * ((int)(t.x      ) >> 24); acc = fmaf((float)p, ra.w, acc);
    p = ((int)(s.y << 24) >> 24) * ((int)(t.y << 24) >> 24); acc = fmaf((float)p, rb.x, acc);
    p = ((int)(s.y << 16) >> 24) * ((int)(t.y << 16) >> 24); acc = fmaf((float)p, rb.y, acc);
    p = ((int)(s.y <<  8) >> 24) * ((int)(t.y <<  8) >> 24); acc = fmaf((float)p, rb.z, acc);
    p = ((int)(s.y      ) >> 24) * ((int)(t.y      ) >> 24); acc = fmaf((float)p, rb.w, acc);
    return acc;
}

// 8 lanes/edge (lane loads 8 int8 feats = 8B; group covers the 64B row),
// 4 edges per group, exact grid, one iteration per group (round-3 shape).
__global__ void __launch_bounds__(256) distmult_i8_kernel(
        const unsigned int* __restrict__ Xq,      // [NUM_NODES, 16] words (64B rows)
        const float* __restrict__ R,              // [NUM_REL, 64] fp32 (hot)
        const unsigned int* __restrict__ maxbits,
        const int*   __restrict__ src,
        const int*   __restrict__ tgt,
        const int*   __restrict__ rel,
        float*       __restrict__ out,
        int num_edges) {
    const int sub = threadIdx.x & 7;
    const int w0  = sub * 2;                      // word offset in 16-word int8 row
    const int f0  = sub * 8;                      // feature offset in fp32 R row
    const float sc  = __uint_as_float(*maxbits) * (1.0f / 127.0f);
    const float sc2 = sc * sc;
    int g = blockIdx.x * 32 + (threadIdx.x >> 3);
    const int gstr = gridDim.x * 32;
    const int ngroups = (num_edges + 3) >> 2;

    for (; g < ngroups; g += gstr) {
        const int e0 = g << 2;
        if (e0 + 3 < num_edges) {
            const vint4 s4 = *reinterpret_cast<const vint4*>(src + e0);
            const vint4 t4 = *reinterpret_cast<const vint4*>(tgt + e0);
            const vint4 r4 = *reinterpret_cast<const vint4*>(rel + e0);

            const vuint2 sv0 = *reinterpret_cast<const vuint2*>(Xq + (size_t)s4.x * 16 + w0);
            const vuint2 sv1 = *reinterpret_cast<const vuint2*>(Xq + (size_t)s4.y * 16 + w0);
            const vuint2 sv2 = *reinterpret_cast<const vuint2*>(Xq + (size_t)s4.z * 16 + w0);
            const vuint2 sv3 = *reinterpret_cast<const vuint2*>(Xq + (size_t)s4.w * 16 + w0);
            const vuint2 tv0 = *reinterpret_cast<const vuint2*>(Xq + (size_t)t4.x * 16 + w0);
            const vuint2 tv1 = *reinterpret_cast<const vuint2*>(Xq + (size_t)t4.y * 16 + w0);
            const vuint2 tv2 = *reinterpret_cast<const vuint2*>(Xq + (size_t)t4.z * 16 + w0);
            const vuint2 tv3 = *reinterpret_cast<const vuint2*>(Xq + (size_t)t4.w * 16 + w0);

            const vfloat4 ra0 = *reinterpret_cast<const vfloat4*>(R + (size_t)r4.x * DIM + f0);
            const vfloat4 rb0 = *reinterpret_cast<const vfloat4*>(R + (size_t)r4.x * DIM + f0 + 4);
            const vfloat4 ra1 = *reinterpret_cast<const vfloat4*>(R + (size_t)r4.y * DIM + f0);
            const vfloat4 rb1 = *reinterpret_cast<const vfloat4*>(R + (size_t)r4.y * DIM + f0 + 4);
            const vfloat4 ra2 = *reinterpret_cast<const vfloat4*>(R + (size_t)r4.z * DIM + f0);
            const vfloat4 rb2 = *reinterpret_cast<const vfloat4*>(R + (size_t)r4.z * DIM + f0 + 4);
            const vfloat4 ra3 = *reinterpret_cast<const vfloat4*>(R + (size_t)r4.w * DIM + f0);
            const vfloat4 rb3 = *reinterpret_cast<const vfloat4*>(R + (size_t)r4.w * DIM + f0 + 4);

            float a0 = dot8_i8(sv0, tv0, ra0, rb0);
            float a1 = dot8_i8(sv1, tv1, ra1, rb1);
            float a2 = dot8_i8(sv2, tv2, ra2, rb2);
            float a3 = dot8_i8(sv3, tv3, ra3, rb3);

            a0 += __shfl_xor(a0, 1, 64); a1 += __shfl_xor(a1, 1, 64);
            a2 += __shfl_xor(a2, 1, 64); a3 += __shfl_xor(a3, 1, 64);
            a0 += __shfl_xor(a0, 2, 64); a1 += __shfl_xor(a1, 2, 64);
            a2 += __shfl_xor(a2, 2, 64); a3 += __shfl_xor(a3, 2, 64);
            a0 += __shfl_xor(a0, 4, 64); a1 += __shfl_xor(a1, 4, 64);
            a2 += __shfl_xor(a2, 4, 64); a3 += __shfl_xor(a3, 4, 64);

            if (sub == 0) {
                vfloat4 o; o.x = a0 * sc2; o.y = a1 * sc2; o.z = a2 * sc2; o.w = a3 * sc2;
                *reinterpret_cast<vfloat4*>(out + e0) = o;
            }
        } else {
            for (int e = e0; e < num_edges; ++e) {
                const int s = src[e], t = tgt[e], r = rel[e];
                const vuint2  sv = *reinterpret_cast<const vuint2*>(Xq + (size_t)s * 16 + w0);
                const vuint2  tv = *reinterpret_cast<const vuint2*>(Xq + (size_t)t * 16 + w0);
                const vfloat4 ra = *reinterpret_cast<const vfloat4*>(R + (size_t)r * DIM + f0);
                const vfloat4 rb = *reinterpret_cast<const vfloat4*>(R + (size_t)r * DIM + f0 + 4);
                float acc = dot8_i8(sv, tv, ra, rb);
                acc += __shfl_xor(acc, 1, 64);
                acc += __shfl_xor(acc, 2, 64);
                acc += __shfl_xor(acc, 4, 64);
                if (sub == 0) out[e] = acc * sc2;
            }
        }
    }
}

// ---------------- fp32 fallback (ws too small) ----------------
__global__ void __launch_bounds__(256) distmult_f32_kernel(
        const float* __restrict__ X, const float* __restrict__ R,
        const int* __restrict__ src, const int* __restrict__ tgt,
        const int* __restrict__ rel, float* __restrict__ out, int num_edges) {
    const int sub = threadIdx.x & 15;
    int e = blockIdx.x * 16 + (threadIdx.x >> 4);
    const int estr = gridDim.x * 16;
    for (; e < num_edges; e += estr) {
        const int s = src[e], t = tgt[e], r = rel[e];
        const float4 sv = *reinterpret_cast<const float4*>(X + (size_t)s * DIM + sub * 4);
        const float4 tv = *reinterpret_cast<const float4*>(X + (size_t)t * DIM + sub * 4);
        const float4 rv = *reinterpret_cast<const float4*>(R + (size_t)r * DIM + sub * 4);
        float acc = sv.x * rv.x * tv.x + sv.y * rv.y * tv.y
                  + sv.z * rv.z * tv.z + sv.w * rv.w * tv.w;
        acc += __shfl_xor(acc, 1, 64);
        acc += __shfl_xor(acc, 2, 64);
        acc += __shfl_xor(acc, 4, 64);
        acc += __shfl_xor(acc, 8, 64);
        if (sub == 0) out[e] = acc;
    }
}

extern "C" void kernel_launch(void* const* d_in, const int* in_sizes, int n_in,
                              void* d_out, int out_size, void* d_ws, size_t ws_size,
                              hipStream_t stream) {
    const float* X         = (const float*)d_in[0];  // (100000, 64) f32
    const float* R         = (const float*)d_in[1];  // (237, 64) f32
    const int*   edge_list = (const int*)d_in[2];    // (2, NUM_EDGES) i32
    const int*   edge_type = (const int*)d_in[3];    // (1, NUM_EDGES) i32
    float*       out       = (float*)d_out;

    const int num_edges = in_sizes[3];
    const int nx        = in_sizes[0];               // X element count (6.4M)
    const int* src = edge_list;
    const int* tgt = edge_list + num_edges;

    // ws layout: [0,4) = absmax bits; [256, 256+nx) = int8 X
    const size_t need = 256 + (size_t)nx;
    if (ws_size >= need && (nx % 16) == 0) {
        unsigned int* maxbits = (unsigned int*)d_ws;
        unsigned int* Xq      = (unsigned int*)((char*)d_ws + 256);

        // must zero the atomicMax slot every call (ws not re-poisoned between replays)
        hipMemsetAsync(maxbits, 0, 4, stream);

        absmax_kernel<<<1024, 256, 0, stream>>>(X, maxbits, nx / 4);

        const int n16 = nx / 16;
        quantize_kernel<<<(n16 + 255) / 256, 256, 0, stream>>>(X, maxbits, Xq, n16);

        const int ngroups = (num_edges + 3) >> 2;    // 4 edges per 8-lane group
        const int gpb = 256 / 8;                     // 32 groups per block
        const int grid = (ngroups + gpb - 1) / gpb;  // exact grid (round-3 shape)
        distmult_i8_kernel<<<grid, 256, 0, stream>>>(
            Xq, R, maxbits, src, tgt, edge_type, out, num_edges);
    } else {
        int grid = (num_edges + 15) / 16;
        if (grid > 8192) grid = 8192;
        distmult_f32_kernel<<<grid, 256, 0, stream>>>(
            X, R, src, tgt, edge_type, out, num_edges);
    }
}

// Round 6
// 57.798 us; speedup vs baseline: 1.8180x; 1.8180x over previous
//
#include <hip/hip_runtime.h>

#define DIM 64

typedef int          vint4   __attribute__((ext_vector_type(4)));
typedef unsigned int vuint2  __attribute__((ext_vector_type(2)));
typedef unsigned int vuint4  __attribute__((ext_vector_type(4)));
typedef float        vfloat4 __attribute__((ext_vector_type(4)));

// ---------------- Kernel 1: fused per-row absmax + int8 quantize ----------------
// 8 lanes per 64-float row. No atomics, no extra pass.
__global__ void __launch_bounds__(256) quantize_rows_kernel(
        const float* __restrict__ X,      // [nrows, 64] fp32
        unsigned int* __restrict__ Xq,    // [nrows, 16] words (64 B int8 rows)
        float* __restrict__ S,            // [nrows] scale = rowmax/127
        int nrows) {
    const int row = blockIdx.x * 32 + (threadIdx.x >> 3);
    if (row >= nrows) return;
    const int sub = threadIdx.x & 7;

    const float* xr = X + (size_t)row * DIM + sub * 8;
    const vfloat4 a = *reinterpret_cast<const vfloat4*>(xr);
    const vfloat4 b = *reinterpret_cast<const vfloat4*>(xr + 4);

    // abs-bits max over this lane's 8 elements (uint compare == float compare for |x|)
    unsigned int m = __float_as_uint(a.x) & 0x7fffffffu;
    m = max(m, __float_as_uint(a.y) & 0x7fffffffu);
    m = max(m, __float_as_uint(a.z) & 0x7fffffffu);
    m = max(m, __float_as_uint(a.w) & 0x7fffffffu);
    m = max(m, __float_as_uint(b.x) & 0x7fffffffu);
    m = max(m, __float_as_uint(b.y) & 0x7fffffffu);
    m = max(m, __float_as_uint(b.z) & 0x7fffffffu);
    m = max(m, __float_as_uint(b.w) & 0x7fffffffu);
    // reduce across the 8-lane row group (xor partners stay in-group)
    m = max(m, (unsigned int)__shfl_xor((int)m, 1, 64));
    m = max(m, (unsigned int)__shfl_xor((int)m, 2, 64));
    m = max(m, (unsigned int)__shfl_xor((int)m, 4, 64));

    const float rowmax = __uint_as_float(m);
    const float inv = (rowmax > 0.0f) ? (127.0f / rowmax) : 0.0f;

    const int q0 = (int)rintf(a.x * inv), q1 = (int)rintf(a.y * inv);
    const int q2 = (int)rintf(a.z * inv), q3 = (int)rintf(a.w * inv);
    const int q4 = (int)rintf(b.x * inv), q5 = (int)rintf(b.y * inv);
    const int q6 = (int)rintf(b.z * inv), q7 = (int)rintf(b.w * inv);
    vuint2 o;
    o.x = (unsigned int)(q0 & 0xff) | ((unsigned int)(q1 & 0xff) << 8) |
          ((unsigned int)(q2 & 0xff) << 16) | ((unsigned int)(q3 & 0xff) << 24);
    o.y = (unsigned int)(q4 & 0xff) | ((unsigned int)(q5 & 0xff) << 8) |
          ((unsigned int)(q6 & 0xff) << 16) | ((unsigned int)(q7 & 0xff) << 24);
    *reinterpret_cast<vuint2*>(Xq + (size_t)row * 16 + sub * 2) = o;

    if (sub == 0) S[row] = rowmax * (1.0f / 127.0f);
}

// ---------------- Score kernel ----------------
// 8 int8 features per lane: exact int products, fp32 weight by R.
__device__ __forceinline__ float dot8_i8(const vuint2& s, const vuint2& t,
                                         const vfloat4& ra, const vfloat4& rb) {
    float acc = 0.f;
    int p;
    p = ((int)(s.x << 24) >> 24) * ((int)(t.x << 24) >> 24); acc = fmaf((float)p, ra.x, acc);
    p = ((int)(s.x << 16) >> 24) * ((int)(t.x << 16) >> 24); acc = fmaf((float)p, ra.y, acc);
    p = ((int)(s.x <<  8) >> 24) * ((int)(t.x <<  8) >> 24); acc = fmaf((float)p, ra.z, acc);
    p = ((int)(s.x      ) >> 24) * ((int)(t.x      ) >> 24); acc = fmaf((float)p, ra.w, acc);
    p = ((int)(s.y << 24) >> 24) * ((int)(t.y << 24) >> 24); acc = fmaf((float)p, rb.x, acc);
    p = ((int)(s.y << 16) >> 24) * ((int)(t.y << 16) >> 24); acc = fmaf((float)p, rb.y, acc);
    p = ((int)(s.y <<  8) >> 24) * ((int)(t.y <<  8) >> 24); acc = fmaf((float)p, rb.z, acc);
    p = ((int)(s.y      ) >> 24) * ((int)(t.y      ) >> 24); acc = fmaf((float)p, rb.w, acc);
    return acc;
}

// 8 lanes/edge (lane loads 8 int8 = 8 B; group covers the 64 B row),
// 4 edges per group, exact grid (round-3 shape, cached loads).
__global__ void __launch_bounds__(256) distmult_i8_kernel(
        const unsigned int* __restrict__ Xq,  // [nrows, 16] words
        const float* __restrict__ R,          // [NUM_REL, 64] fp32 (hot)
        const float* __restrict__ S,          // [nrows] per-row scales (L2-resident)
        const int*   __restrict__ src,
        const int*   __restrict__ tgt,
        const int*   __restrict__ rel,
        float*       __restrict__ out,
        int num_edges) {
    const int sub = threadIdx.x & 7;
    const int w0  = sub * 2;                  // word offset in 16-word int8 row
    const int f0  = sub * 8;                  // feature offset in fp32 R row
    int g = blockIdx.x * 32 + (threadIdx.x >> 3);
    const int gstr = gridDim.x * 32;
    const int ngroups = (num_edges + 3) >> 2;

    for (; g < ngroups; g += gstr) {
        const int e0 = g << 2;
        if (e0 + 3 < num_edges) {
            const vint4 s4 = *reinterpret_cast<const vint4*>(src + e0);
            const vint4 t4 = *reinterpret_cast<const vint4*>(tgt + e0);
            const vint4 r4 = *reinterpret_cast<const vint4*>(rel + e0);

            const vuint2 sv0 = *reinterpret_cast<const vuint2*>(Xq + (size_t)s4.x * 16 + w0);
            const vuint2 sv1 = *reinterpret_cast<const vuint2*>(Xq + (size_t)s4.y * 16 + w0);
            const vuint2 sv2 = *reinterpret_cast<const vuint2*>(Xq + (size_t)s4.z * 16 + w0);
            const vuint2 sv3 = *reinterpret_cast<const vuint2*>(Xq + (size_t)s4.w * 16 + w0);
            const vuint2 tv0 = *reinterpret_cast<const vuint2*>(Xq + (size_t)t4.x * 16 + w0);
            const vuint2 tv1 = *reinterpret_cast<const vuint2*>(Xq + (size_t)t4.y * 16 + w0);
            const vuint2 tv2 = *reinterpret_cast<const vuint2*>(Xq + (size_t)t4.z * 16 + w0);
            const vuint2 tv3 = *reinterpret_cast<const vuint2*>(Xq + (size_t)t4.w * 16 + w0);

            // per-edge scale products (4 B broadcast gathers, 400 KB L2-hot table)
            const float sc0 = S[s4.x] * S[t4.x];
            const float sc1 = S[s4.y] * S[t4.y];
            const float sc2 = S[s4.z] * S[t4.z];
            const float sc3 = S[s4.w] * S[t4.w];

            const vfloat4 ra0 = *reinterpret_cast<const vfloat4*>(R + (size_t)r4.x * DIM + f0);
            const vfloat4 rb0 = *reinterpret_cast<const vfloat4*>(R + (size_t)r4.x * DIM + f0 + 4);
            const vfloat4 ra1 = *reinterpret_cast<const vfloat4*>(R + (size_t)r4.y * DIM + f0);
            const vfloat4 rb1 = *reinterpret_cast<const vfloat4*>(R + (size_t)r4.y * DIM + f0 + 4);
            const vfloat4 ra2 = *reinterpret_cast<const vfloat4*>(R + (size_t)r4.z * DIM + f0);
            const vfloat4 rb2 = *reinterpret_cast<const vfloat4*>(R + (size_t)r4.z * DIM + f0 + 4);
            const vfloat4 ra3 = *reinterpret_cast<const vfloat4*>(R + (size_t)r4.w * DIM + f0);
            const vfloat4 rb3 = *reinterpret_cast<const vfloat4*>(R + (size_t)r4.w * DIM + f0 + 4);

            float a0 = dot8_i8(sv0, tv0, ra0, rb0);
            float a1 = dot8_i8(sv1, tv1, ra1, rb1);
            float a2 = dot8_i8(sv2, tv2, ra2, rb2);
            float a3 = dot8_i8(sv3, tv3, ra3, rb3);

            a0 += __shfl_xor(a0, 1, 64); a1 += __shfl_xor(a1, 1, 64);
            a2 += __shfl_xor(a2, 1, 64); a3 += __shfl_xor(a3, 1, 64);
            a0 += __shfl_xor(a0, 2, 64); a1 += __shfl_xor(a1, 2, 64);
            a2 += __shfl_xor(a2, 2, 64); a3 += __shfl_xor(a3, 2, 64);
            a0 += __shfl_xor(a0, 4, 64); a1 += __shfl_xor(a1, 4, 64);
            a2 += __shfl_xor(a2, 4, 64); a3 += __shfl_xor(a3, 4, 64);

            if (sub == 0) {
                vfloat4 o;
                o.x = a0 * sc0; o.y = a1 * sc1; o.z = a2 * sc2; o.w = a3 * sc3;
                *reinterpret_cast<vfloat4*>(out + e0) = o;
            }
        } else {
            for (int e = e0; e < num_edges; ++e) {
                const int s = src[e], t = tgt[e], r = rel[e];
                const vuint2  sv = *reinterpret_cast<const vuint2*>(Xq + (size_t)s * 16 + w0);
                const vuint2  tv = *reinterpret_cast<const vuint2*>(Xq + (size_t)t * 16 + w0);
                const vfloat4 ra = *reinterpret_cast<const vfloat4*>(R + (size_t)r * DIM + f0);
                const vfloat4 rb = *reinterpret_cast<const vfloat4*>(R + (size_t)r * DIM + f0 + 4);
                float acc = dot8_i8(sv, tv, ra, rb);
                acc += __shfl_xor(acc, 1, 64);
                acc += __shfl_xor(acc, 2, 64);
                acc += __shfl_xor(acc, 4, 64);
                if (sub == 0) out[e] = acc * S[s] * S[t];
            }
        }
    }
}

// ---------------- fp32 fallback (ws too small) ----------------
__global__ void __launch_bounds__(256) distmult_f32_kernel(
        const float* __restrict__ X, const float* __restrict__ R,
        const int* __restrict__ src, const int* __restrict__ tgt,
        const int* __restrict__ rel, float* __restrict__ out, int num_edges) {
    const int sub = threadIdx.x & 15;
    int e = blockIdx.x * 16 + (threadIdx.x >> 4);
    const int estr = gridDim.x * 16;
    for (; e < num_edges; e += estr) {
        const int s = src[e], t = tgt[e], r = rel[e];
        const float4 sv = *reinterpret_cast<const float4*>(X + (size_t)s * DIM + sub * 4);
        const float4 tv = *reinterpret_cast<const float4*>(X + (size_t)t * DIM + sub * 4);
        const float4 rv = *reinterpret_cast<const float4*>(R + (size_t)r * DIM + sub * 4);
        float acc = sv.x * rv.x * tv.x + sv.y * rv.y * tv.y
                  + sv.z * rv.z * tv.z + sv.w * rv.w * tv.w;
        acc += __shfl_xor(acc, 1, 64);
        acc += __shfl_xor(acc, 2, 64);
        acc += __shfl_xor(acc, 4, 64);
        acc += __shfl_xor(acc, 8, 64);
        if (sub == 0) out[e] = acc;
    }
}

extern "C" void kernel_launch(void* const* d_in, const int* in_sizes, int n_in,
                              void* d_out, int out_size, void* d_ws, size_t ws_size,
                              hipStream_t stream) {
    const float* X         = (const float*)d_in[0];  // (100000, 64) f32
    const float* R         = (const float*)d_in[1];  // (237, 64) f32
    const int*   edge_list = (const int*)d_in[2];    // (2, NUM_EDGES) i32
    const int*   edge_type = (const int*)d_in[3];    // (1, NUM_EDGES) i32
    float*       out       = (float*)d_out;

    const int num_edges = in_sizes[3];
    const int nx        = in_sizes[0];               // 6.4M floats
    const int nrows     = nx / DIM;                  // 100000
    const int* src = edge_list;
    const int* tgt = edge_list + num_edges;

    // ws layout: [0, nrows*4) = scales; [512KB-aligned, +nx) = int8 X
    const size_t sc_bytes = ((size_t)nrows * 4 + 511) & ~(size_t)511;
    const size_t need = sc_bytes + (size_t)nx;
    if (ws_size >= need && (nx % DIM) == 0) {
        float*        Sv = (float*)d_ws;
        unsigned int* Xq = (unsigned int*)((char*)d_ws + sc_bytes);

        // fused per-row absmax + quantize: 32 rows per 256-thread block
        quantize_rows_kernel<<<(nrows + 31) / 32, 256, 0, stream>>>(X, Xq, Sv, nrows);

        const int ngroups = (num_edges + 3) >> 2;    // 4 edges per 8-lane group
        const int gpb = 256 / 8;                     // 32 groups per block
        const int grid = (ngroups + gpb - 1) / gpb;  // exact grid
        distmult_i8_kernel<<<grid, 256, 0, stream>>>(
            Xq, R, Sv, src, tgt, edge_type, out, num_edges);
    } else {
        int grid = (num_edges + 15) / 16;
        if (grid > 8192) grid = 8192;
        distmult_f32_kernel<<<grid, 256, 0, stream>>>(
            X, R, src, tgt, edge_type, out, num_edges);
    }
}

// Round 7
// 48.839 us; speedup vs baseline: 2.1515x; 1.1834x over previous
//
#include <hip/hip_runtime.h>

#define DIM 64
#define MAX_REL 256          // LDS R-cache capacity (rows)
#define RPAD 68              // padded LDS row stride in floats (spreads banks)

typedef int          vint4   __attribute__((ext_vector_type(4)));
typedef unsigned int vuint2  __attribute__((ext_vector_type(2)));
typedef float        vfloat4 __attribute__((ext_vector_type(4)));

// ---------------- Kernel 1: fused per-row absmax + int8 quantize ----------------
__global__ void __launch_bounds__(256) quantize_rows_kernel(
        const float* __restrict__ X,      // [nrows, 64] fp32
        unsigned int* __restrict__ Xq,    // [nrows, 16] words (64 B int8 rows)
        float* __restrict__ S,            // [nrows] scale = rowmax/127
        int nrows) {
    const int row = blockIdx.x * 32 + (threadIdx.x >> 3);
    if (row >= nrows) return;
    const int sub = threadIdx.x & 7;

    const float* xr = X + (size_t)row * DIM + sub * 8;
    const vfloat4 a = *reinterpret_cast<const vfloat4*>(xr);
    const vfloat4 b = *reinterpret_cast<const vfloat4*>(xr + 4);

    unsigned int m = __float_as_uint(a.x) & 0x7fffffffu;
    m = max(m, __float_as_uint(a.y) & 0x7fffffffu);
    m = max(m, __float_as_uint(a.z) & 0x7fffffffu);
    m = max(m, __float_as_uint(a.w) & 0x7fffffffu);
    m = max(m, __float_as_uint(b.x) & 0x7fffffffu);
    m = max(m, __float_as_uint(b.y) & 0x7fffffffu);
    m = max(m, __float_as_uint(b.z) & 0x7fffffffu);
    m = max(m, __float_as_uint(b.w) & 0x7fffffffu);
    m = max(m, (unsigned int)__shfl_xor((int)m, 1, 64));
    m = max(m, (unsigned int)__shfl_xor((int)m, 2, 64));
    m = max(m, (unsigned int)__shfl_xor((int)m, 4, 64));

    const float rowmax = __uint_as_float(m);
    const float inv = (rowmax > 0.0f) ? (127.0f / rowmax) : 0.0f;

    const int q0 = (int)rintf(a.x * inv), q1 = (int)rintf(a.y * inv);
    const int q2 = (int)rintf(a.z * inv), q3 = (int)rintf(a.w * inv);
    const int q4 = (int)rintf(b.x * inv), q5 = (int)rintf(b.y * inv);
    const int q6 = (int)rintf(b.z * inv), q7 = (int)rintf(b.w * inv);
    vuint2 o;
    o.x = (unsigned int)(q0 & 0xff) | ((unsigned int)(q1 & 0xff) << 8) |
          ((unsigned int)(q2 & 0xff) << 16) | ((unsigned int)(q3 & 0xff) << 24);
    o.y = (unsigned int)(q4 & 0xff) | ((unsigned int)(q5 & 0xff) << 8) |
          ((unsigned int)(q6 & 0xff) << 16) | ((unsigned int)(q7 & 0xff) << 24);
    *reinterpret_cast<vuint2*>(Xq + (size_t)row * 16 + sub * 2) = o;

    if (sub == 0) S[row] = rowmax * (1.0f / 127.0f);
}

// ---------------- int8 dot helper ----------------
__device__ __forceinline__ float dot8_i8(const vuint2& s, const vuint2& t,
                                         const vfloat4& ra, const vfloat4& rb) {
    float acc = 0.f;
    int p;
    p = ((int)(s.x << 24) >> 24) * ((int)(t.x << 24) >> 24); acc = fmaf((float)p, ra.x, acc);
    p = ((int)(s.x << 16) >> 24) * ((int)(t.x << 16) >> 24); acc = fmaf((float)p, ra.y, acc);
    p = ((int)(s.x <<  8) >> 24) * ((int)(t.x <<  8) >> 24); acc = fmaf((float)p, ra.z, acc);
    p = ((int)(s.x      ) >> 24) * ((int)(t.x      ) >> 24); acc = fmaf((float)p, ra.w, acc);
    p = ((int)(s.y << 24) >> 24) * ((int)(t.y << 24) >> 24); acc = fmaf((float)p, rb.x, acc);
    p = ((int)(s.y << 16) >> 24) * ((int)(t.y << 16) >> 24); acc = fmaf((float)p, rb.y, acc);
    p = ((int)(s.y <<  8) >> 24) * ((int)(t.y <<  8) >> 24); acc = fmaf((float)p, rb.z, acc);
    p = ((int)(s.y      ) >> 24) * ((int)(t.y      ) >> 24); acc = fmaf((float)p, rb.w, acc);
    return acc;
}

// ---------------- Score kernel: R staged in LDS (removes R from the TA path) ----
// 512 threads = 64 groups of 8 lanes; 4 edges/group; persistent grid-stride.
__global__ void __launch_bounds__(512) distmult_i8_lds_kernel(
        const unsigned int* __restrict__ Xq,  // [nrows, 16] words
        const float* __restrict__ R,          // [nrel, 64] fp32
        const float* __restrict__ S,          // [nrows] per-row scales
        const int*   __restrict__ src,
        const int*   __restrict__ tgt,
        const int*   __restrict__ rel,
        float*       __restrict__ out,
        int num_edges, int nrel) {
    __shared__ float Rs[MAX_REL * RPAD];      // 68 KB: 2 blocks/CU, 16 waves/CU

    // ---- stage R into LDS (coalesced float4, padded rows) ----
    for (int i = threadIdx.x; i < nrel * 16; i += 512) {
        const int r = i >> 4, c = (i & 15) * 4;
        *reinterpret_cast<vfloat4*>(&Rs[r * RPAD + c]) =
            *reinterpret_cast<const vfloat4*>(R + (size_t)r * DIM + c);
    }
    __syncthreads();

    const int sub = threadIdx.x & 7;
    const int w0  = sub * 2;                  // word offset in 16-word int8 row
    const int f0  = sub * 8;                  // feature offset in R row
    int g = blockIdx.x * 64 + (threadIdx.x >> 3);
    const int gstr = gridDim.x * 64;
    const int ngroups = (num_edges + 3) >> 2;

    for (; g < ngroups; g += gstr) {
        const int e0 = g << 2;
        if (e0 + 3 < num_edges) {
            const vint4 s4 = *reinterpret_cast<const vint4*>(src + e0);
            const vint4 t4 = *reinterpret_cast<const vint4*>(tgt + e0);
            const vint4 r4 = *reinterpret_cast<const vint4*>(rel + e0);

            const vuint2 sv0 = *reinterpret_cast<const vuint2*>(Xq + (size_t)s4.x * 16 + w0);
            const vuint2 sv1 = *reinterpret_cast<const vuint2*>(Xq + (size_t)s4.y * 16 + w0);
            const vuint2 sv2 = *reinterpret_cast<const vuint2*>(Xq + (size_t)s4.z * 16 + w0);
            const vuint2 sv3 = *reinterpret_cast<const vuint2*>(Xq + (size_t)s4.w * 16 + w0);
            const vuint2 tv0 = *reinterpret_cast<const vuint2*>(Xq + (size_t)t4.x * 16 + w0);
            const vuint2 tv1 = *reinterpret_cast<const vuint2*>(Xq + (size_t)t4.y * 16 + w0);
            const vuint2 tv2 = *reinterpret_cast<const vuint2*>(Xq + (size_t)t4.z * 16 + w0);
            const vuint2 tv3 = *reinterpret_cast<const vuint2*>(Xq + (size_t)t4.w * 16 + w0);

            const float sc0 = S[s4.x] * S[t4.x];
            const float sc1 = S[s4.y] * S[t4.y];
            const float sc2 = S[s4.z] * S[t4.z];
            const float sc3 = S[s4.w] * S[t4.w];

            // R from LDS: zero TA cost
            const float* r0 = &Rs[r4.x * RPAD + f0];
            const float* r1 = &Rs[r4.y * RPAD + f0];
            const float* r2 = &Rs[r4.z * RPAD + f0];
            const float* r3 = &Rs[r4.w * RPAD + f0];
            const vfloat4 ra0 = *reinterpret_cast<const vfloat4*>(r0);
            const vfloat4 rb0 = *reinterpret_cast<const vfloat4*>(r0 + 4);
            const vfloat4 ra1 = *reinterpret_cast<const vfloat4*>(r1);
            const vfloat4 rb1 = *reinterpret_cast<const vfloat4*>(r1 + 4);
            const vfloat4 ra2 = *reinterpret_cast<const vfloat4*>(r2);
            const vfloat4 rb2 = *reinterpret_cast<const vfloat4*>(r2 + 4);
            const vfloat4 ra3 = *reinterpret_cast<const vfloat4*>(r3);
            const vfloat4 rb3 = *reinterpret_cast<const vfloat4*>(r3 + 4);

            float a0 = dot8_i8(sv0, tv0, ra0, rb0);
            float a1 = dot8_i8(sv1, tv1, ra1, rb1);
            float a2 = dot8_i8(sv2, tv2, ra2, rb2);
            float a3 = dot8_i8(sv3, tv3, ra3, rb3);

            a0 += __shfl_xor(a0, 1, 64); a1 += __shfl_xor(a1, 1, 64);
            a2 += __shfl_xor(a2, 1, 64); a3 += __shfl_xor(a3, 1, 64);
            a0 += __shfl_xor(a0, 2, 64); a1 += __shfl_xor(a1, 2, 64);
            a2 += __shfl_xor(a2, 2, 64); a3 += __shfl_xor(a3, 2, 64);
            a0 += __shfl_xor(a0, 4, 64); a1 += __shfl_xor(a1, 4, 64);
            a2 += __shfl_xor(a2, 4, 64); a3 += __shfl_xor(a3, 4, 64);

            if (sub == 0) {
                vfloat4 o;
                o.x = a0 * sc0; o.y = a1 * sc1; o.z = a2 * sc2; o.w = a3 * sc3;
                *reinterpret_cast<vfloat4*>(out + e0) = o;
            }
        } else {
            for (int e = e0; e < num_edges; ++e) {
                const int s = src[e], t = tgt[e], r = rel[e];
                const vuint2 sv = *reinterpret_cast<const vuint2*>(Xq + (size_t)s * 16 + w0);
                const vuint2 tv = *reinterpret_cast<const vuint2*>(Xq + (size_t)t * 16 + w0);
                const float* rr = &Rs[r * RPAD + f0];
                const vfloat4 ra = *reinterpret_cast<const vfloat4*>(rr);
                const vfloat4 rb = *reinterpret_cast<const vfloat4*>(rr + 4);
                float acc = dot8_i8(sv, tv, ra, rb);
                acc += __shfl_xor(acc, 1, 64);
                acc += __shfl_xor(acc, 2, 64);
                acc += __shfl_xor(acc, 4, 64);
                if (sub == 0) out[e] = acc * S[s] * S[t];
            }
        }
    }
}

// ---------------- fp32 fallback (ws too small or nrel > MAX_REL) ----------------
__global__ void __launch_bounds__(256) distmult_f32_kernel(
        const float* __restrict__ X, const float* __restrict__ R,
        const int* __restrict__ src, const int* __restrict__ tgt,
        const int* __restrict__ rel, float* __restrict__ out, int num_edges) {
    const int sub = threadIdx.x & 15;
    int e = blockIdx.x * 16 + (threadIdx.x >> 4);
    const int estr = gridDim.x * 16;
    for (; e < num_edges; e += estr) {
        const int s = src[e], t = tgt[e], r = rel[e];
        const float4 sv = *reinterpret_cast<const float4*>(X + (size_t)s * DIM + sub * 4);
        const float4 tv = *reinterpret_cast<const float4*>(X + (size_t)t * DIM + sub * 4);
        const float4 rv = *reinterpret_cast<const float4*>(R + (size_t)r * DIM + sub * 4);
        float acc = sv.x * rv.x * tv.x + sv.y * rv.y * tv.y
                  + sv.z * rv.z * tv.z + sv.w * rv.w * tv.w;
        acc += __shfl_xor(acc, 1, 64);
        acc += __shfl_xor(acc, 2, 64);
        acc += __shfl_xor(acc, 4, 64);
        acc += __shfl_xor(acc, 8, 64);
        if (sub == 0) out[e] = acc;
    }
}

extern "C" void kernel_launch(void* const* d_in, const int* in_sizes, int n_in,
                              void* d_out, int out_size, void* d_ws, size_t ws_size,
                              hipStream_t stream) {
    const float* X         = (const float*)d_in[0];  // (100000, 64) f32
    const float* R         = (const float*)d_in[1];  // (237, 64) f32
    const int*   edge_list = (const int*)d_in[2];    // (2, NUM_EDGES) i32
    const int*   edge_type = (const int*)d_in[3];    // (1, NUM_EDGES) i32
    float*       out       = (float*)d_out;

    const int num_edges = in_sizes[3];
    const int nx        = in_sizes[0];               // 6.4M floats
    const int nrows     = nx / DIM;                  // 100000
    const int nrel      = in_sizes[1] / DIM;         // 237
    const int* src = edge_list;
    const int* tgt = edge_list + num_edges;

    const size_t sc_bytes = ((size_t)nrows * 4 + 511) & ~(size_t)511;
    const size_t need = sc_bytes + (size_t)nx;
    if (ws_size >= need && (nx % DIM) == 0 && nrel <= MAX_REL) {
        float*        Sv = (float*)d_ws;
        unsigned int* Xq = (unsigned int*)((char*)d_ws + sc_bytes);

        quantize_rows_kernel<<<(nrows + 31) / 32, 256, 0, stream>>>(X, Xq, Sv, nrows);

        // Persistent blocks: 2 per CU (68 KB LDS each), R staged once per block.
        const int ngroups = (num_edges + 3) >> 2;
        int grid = 512;
        const int max_grid = (ngroups + 63) / 64;
        if (grid > max_grid) grid = max_grid;
        distmult_i8_lds_kernel<<<grid, 512, 0, stream>>>(
            Xq, R, Sv, src, tgt, edge_type, out, num_edges, nrel);
    } else {
        int grid = (num_edges + 15) / 16;
        if (grid > 8192) grid = 8192;
        distmult_f32_kernel<<<grid, 256, 0, stream>>>(
            X, R, src, tgt, edge_type, out, num_edges);
    }
}